// Round 7
// baseline (10018.961 us; speedup 1.0000x reference)
//
#include <hip/hip_runtime.h>
#include <hip/hip_bf16.h>

// ---------------------------------------------------------------------------
// GRU with per-timestep BatchNorm on the input projections.
//   T=512, B=64, I=H=512.
// Round 4 -> 5 (3rd submit; rounds 5 and 6 both hit GPUAcquisitionTimeout --
// kernel is UNCHANGED and still unbenched; no evidence to justify edits):
// flag-based barriers cost 4 serialized LLC round-trips per exchange (payload
// ack -> flag store -> flag detect -> payload load). Now the payload is
// SELF-VALIDATING: every exchanged word is a u64 {epoch | 2xbf16} stored with
// one relaxed agent-scope atomic; consumers poll the words they need until the
// tag matches. 2 LLC hops per exchange, no flags, no fences, no
// __syncthreads in the scan loop at all.
// Overwrite safety (induction, desk-checked both buffers): a word can only
// advance to tag ev+1 after ALL WGs' polls needing tag ev have completed, via
// the rh/h publish gating chain; data deps guarantee loads were serviced
// before the dependent store is issued. One writer per word per epoch (no
// ABA); tags 1..513 never alias the 0xAA ws-poison, which the harness
// re-applies before every replay -> graph-replay-safe with zero init.
// ---------------------------------------------------------------------------

using bf16x8 = __attribute__((ext_vector_type(8))) short;
using f32x4  = __attribute__((ext_vector_type(4))) float;
using fvec4  = __attribute__((ext_vector_type(4))) float;
using s16x4  = __attribute__((ext_vector_type(4))) short;

#define NWG 32

static __device__ __forceinline__ unsigned short f2bf(float f) {
  union { float ff; unsigned int i; } v; v.ff = f;
  unsigned int x = v.i;
  x += 0x7fffu + ((x >> 16) & 1u);   // RNE
  return (unsigned short)(x >> 16);
}
static __device__ __forceinline__ float h2f(unsigned short u) {
  union { unsigned short s; _Float16 h; } v; v.s = u; return (float)v.h;
}
static __device__ __forceinline__ unsigned short f2h(float f) {
  union { unsigned short s; _Float16 h; } v; v.h = (_Float16)f; return v.s;
}
static __device__ __forceinline__ float sigmoidf_(float x) {
  return 1.0f / (1.0f + __expf(-x));
}
static __device__ __forceinline__ float tanhf_(float x) {
  return 2.0f / (1.0f + __expf(-2.0f * x)) - 1.0f;
}

// ---------------- phase 1: ub_m = BN(x @ U_m^T) + W_m_b  (fp16 out) --------
// 64x64 tile = one timestep x batch(64) x 64 cols. BK=64, 4 waves,
// mfma_f32_16x16x32_bf16. BN stats from fp32 accs: shfl over kseg (16 rows)
// then LDS over the 4 waves (64 rows). Output layout [t][col][batch].
__global__ __launch_bounds__(256) void proj_gemm(
    const float* __restrict__ x,
    const float* __restrict__ Uz, const float* __restrict__ Ur,
    const float* __restrict__ Uh,
    const float* __restrict__ Wzb, const float* __restrict__ Wrb,
    const float* __restrict__ Whb,
    const float* __restrict__ gamma, const float* __restrict__ beta,
    unsigned short* __restrict__ ubz, unsigned short* __restrict__ ubr,
    unsigned short* __restrict__ ubh)
{
  const int mt = blockIdx.x, nt = blockIdx.y, mat = blockIdx.z;
  const float* U  = (mat == 0) ? Uz  : (mat == 1 ? Ur  : Uh);
  const float* Wb = (mat == 0) ? Wzb : (mat == 1 ? Wrb : Whb);
  unsigned short* uo = (mat == 0) ? ubz : (mat == 1 ? ubr : ubh);

  __shared__ short lA[4096];   // [64][64] bf16, 128B rows, XOR-swizzled
  __shared__ short lB[4096];

  const int tid = threadIdx.x;
  const int wave = tid >> 6, lane = tid & 63;
  const int fl = lane & 15, kseg = lane >> 4;

  f32x4 acc[4];
  #pragma unroll
  for (int n = 0; n < 4; ++n) acc[n] = f32x4{0.f, 0.f, 0.f, 0.f};

  const float* xb = x + (size_t)mt * 64 * 512;
  const float* Ub = U + (size_t)nt * 64 * 512;

  for (int kt = 0; kt < 8; ++kt) {
    __syncthreads();
    #pragma unroll
    for (int c = 0; c < 2; ++c) {
      const int chunk = tid + 256 * c;       // 0..511
      const int row = chunk >> 3, kc = chunk & 7;
      const int lb = row * 128 + ((kc * 16) ^ ((row & 7) << 4));
      {
        const float* g = xb + (size_t)row * 512 + kt * 64 + kc * 8;
        fvec4 a0 = *(const fvec4*)g, a1 = *(const fvec4*)(g + 4);
        bf16x8 p;
        p[0] = (short)f2bf(a0[0]); p[1] = (short)f2bf(a0[1]);
        p[2] = (short)f2bf(a0[2]); p[3] = (short)f2bf(a0[3]);
        p[4] = (short)f2bf(a1[0]); p[5] = (short)f2bf(a1[1]);
        p[6] = (short)f2bf(a1[2]); p[7] = (short)f2bf(a1[3]);
        *(bf16x8*)((char*)lA + lb) = p;
      }
      {
        const float* g = Ub + (size_t)row * 512 + kt * 64 + kc * 8;
        fvec4 a0 = *(const fvec4*)g, a1 = *(const fvec4*)(g + 4);
        bf16x8 p;
        p[0] = (short)f2bf(a0[0]); p[1] = (short)f2bf(a0[1]);
        p[2] = (short)f2bf(a0[2]); p[3] = (short)f2bf(a0[3]);
        p[4] = (short)f2bf(a1[0]); p[5] = (short)f2bf(a1[1]);
        p[6] = (short)f2bf(a1[2]); p[7] = (short)f2bf(a1[3]);
        *(bf16x8*)((char*)lB + lb) = p;
      }
    }
    __syncthreads();
    #pragma unroll
    for (int kk = 0; kk < 2; ++kk) {
      const int ar = wave * 16 + fl;
      bf16x8 af = *(const bf16x8*)((char*)lA + ar * 128 +
                    ((kk * 64 + kseg * 16) ^ ((ar & 7) << 4)));
      #pragma unroll
      for (int n = 0; n < 4; ++n) {
        const int br = n * 16 + fl;
        bf16x8 bfr = *(const bf16x8*)((char*)lB + br * 128 +
                      ((kk * 64 + kseg * 16) ^ ((br & 7) << 4)));
        acc[n] = __builtin_amdgcn_mfma_f32_16x16x32_bf16(af, bfr, acc[n], 0, 0, 0);
      }
    }
  }

  // ---- BN epilogue: exact batch stats (all 64 rows), from fp32 accs ----
  float sn[4], qn[4];
  #pragma unroll
  for (int n = 0; n < 4; ++n) {
    sn[n] = acc[n][0] + acc[n][1] + acc[n][2] + acc[n][3];
    qn[n] = acc[n][0]*acc[n][0] + acc[n][1]*acc[n][1]
          + acc[n][2]*acc[n][2] + acc[n][3]*acc[n][3];
    sn[n] += __shfl_xor(sn[n], 16); qn[n] += __shfl_xor(qn[n], 16);
    sn[n] += __shfl_xor(sn[n], 32); qn[n] += __shfl_xor(qn[n], 32);
  }
  __syncthreads();                       // all MFMA LDS reads done; reuse lA/lB
  float* sArr = (float*)lA;              // [wave*64 + n*16 + fl]
  float* qArr = (float*)lB;
  if (kseg == 0) {
    #pragma unroll
    for (int n = 0; n < 4; ++n) {
      sArr[wave * 64 + n * 16 + fl] = sn[n];
      qArr[wave * 64 + n * 16 + fl] = qn[n];
    }
  }
  __syncthreads();

  const int c0 = nt * 64;
  const int b0 = wave * 16 + kseg * 4;     // batch base for this thread
  #pragma unroll
  for (int n = 0; n < 4; ++n) {
    const int idx = n * 16 + fl;
    const float s = sArr[idx] + sArr[64+idx] + sArr[128+idx] + sArr[192+idx];
    const float q = qArr[idx] + qArr[64+idx] + qArr[128+idx] + qArr[192+idx];
    const float mu = s * 0.015625f;
    const float rs = rsqrtf(q * 0.015625f - mu * mu + 1e-5f);
    const int col = c0 + idx;
    const float gb  = gamma[col] * rs;
    const float ofs = beta[col] + Wb[col] - gb * mu;   // fold W bias here
    s16x4 pk;
    #pragma unroll
    for (int i = 0; i < 4; ++i)
      pk[i] = (short)f2h(gb * acc[n][i] + ofs);
    // transposed layout: [t][col][batch]
    *(s16x4*)(uo + ((size_t)mt * 512 + col) * 64 + b0) = pk;
  }
}

// ---------------- phase 2: persistent GRU scan (tagged-word exchange) ------
__global__ __launch_bounds__(256) void gru_scan(
    const float* __restrict__ h0,
    const float* __restrict__ Wz, const float* __restrict__ Wr,
    const float* __restrict__ Wh,
    const unsigned short* __restrict__ ubz, const unsigned short* __restrict__ ubr,
    const unsigned short* __restrict__ ubh,
    unsigned long long* __restrict__ hbuf,   // u64[64][256]: {epoch|2xbf16}
    unsigned long long* __restrict__ rhbuf,  // same
    float* __restrict__ out)
{
  const int wg = blockIdx.x;           // owns cols [wg*16, wg*16+16)
  const int tid = threadIdx.x;
  const int wave = tid >> 6, lane = tid & 63;
  const int fl = lane & 15, kseg = lane >> 4;
  const int col = wg * 16 + fl;        // this lane's output column
  const int row0 = wave * 16 + kseg * 4;   // first of 4 C-rows (batch)
  const int hrow = wave * 16 + fl;         // A-frag row (batch)

  // W slices, bf16, [mat][16 rows][512 k], 1KB rows, XOR-swizzled
  __shared__ short lW[24576];

  for (int c = tid; c < 3072; c += 256) {        // 8-elem chunks
    const int m = c >> 10, rem = c & 1023;
    const int r = rem >> 6, kc = rem & 63;
    const float* W = (m == 0) ? Wz : (m == 1 ? Wr : Wh);
    const float* g = W + (size_t)(wg * 16 + r) * 512 + kc * 8;
    bf16x8 p;
    #pragma unroll
    for (int j = 0; j < 8; ++j) p[j] = (short)f2bf(g[j]);
    *(bf16x8*)((char*)lW + m * 16384 + r * 1024 + ((kc * 16) ^ ((r & 7) << 4))) = p;
  }
  __syncthreads();     // lW ready (only intra-WG sync in the kernel)

  // publish 4 bf16 values (rows row0..+3, this lane's col) as tagged words.
  // lane pairs pack (even col | odd col<<16); each thread stores 2 words.
  auto publish4 = [&](unsigned long long* buf, unsigned int ev, const float v0,
                      const float v1, const float v2, const float v3) {
    float vv[4] = {v0, v1, v2, v3};
    #pragma unroll
    for (int i = 0; i < 4; ++i) {
      unsigned int mine = f2bf(vv[i]);
      unsigned int other = (unsigned int)__shfl_xor((int)mine, 1);
      unsigned int word = (fl & 1) ? ((mine << 16) | other)
                                   : (mine | (other << 16));
      if ((fl & 1) == (i & 1))
        __hip_atomic_store(&buf[(row0 + i) * 256 + (col >> 1)],
                           ((unsigned long long)ev << 32) | (unsigned long long)word,
                           __ATOMIC_RELAXED, __HIP_MEMORY_SCOPE_AGENT);
    }
  };

  // poll 8 A-fragments (rows=hrow, K-chunks kk0..kk0+7) until tags match ev.
  auto poll8 = [&](const unsigned long long* buf, unsigned int ev, int kk0,
                   bf16x8* dst) {
    const unsigned long long* base = buf + hrow * 256 + kseg * 4;
    unsigned long long w[32];
    for (;;) {
      #pragma unroll
      for (int j = 0; j < 8; ++j) {
        #pragma unroll
        for (int q = 0; q < 4; ++q)
          w[j * 4 + q] = __hip_atomic_load(base + (kk0 + j) * 16 + q,
                                           __ATOMIC_RELAXED,
                                           __HIP_MEMORY_SCOPE_AGENT);
      }
      bool ok = true;
      #pragma unroll
      for (int j = 0; j < 32; ++j)
        ok &= ((unsigned int)(w[j] >> 32) == ev);
      if (ok) break;
    }
    #pragma unroll
    for (int j = 0; j < 8; ++j) {
      union { unsigned int d[4]; bf16x8 f; } u;
      #pragma unroll
      for (int q = 0; q < 4; ++q) u.d[q] = (unsigned int)w[j * 4 + q];
      dst[j] = u.f;
    }
  };

  // own h columns, fp32, never leave registers
  float hown[4];
  #pragma unroll
  for (int i = 0; i < 4; ++i)
    hown[i] = h0[(size_t)(row0 + i) * 512 + col];
  publish4(hbuf, 1u, hown[0], hown[1], hown[2], hown[3]);

  // prefetch BN-ed u for t=0 (biases folded; layout [t][col][batch])
  float uzv[4], urv[4], uhv[4];
  {
    const size_t ub = ((size_t)col) * 64 + row0;
    s16x4 az = *(const s16x4*)(ubz + ub);
    s16x4 ar = *(const s16x4*)(ubr + ub);
    s16x4 ah = *(const s16x4*)(ubh + ub);
    #pragma unroll
    for (int i = 0; i < 4; ++i) {
      uzv[i] = h2f((unsigned short)az[i]);
      urv[i] = h2f((unsigned short)ar[i]);
      uhv[i] = h2f((unsigned short)ah[i]);
    }
  }

  for (int t = 0; t < 512; ++t) {
    const unsigned int ev = (unsigned int)t + 1u;

    // ---- phase 1: gather h(t) fragments (poll directly on tagged payload)
    bf16x8 af[16];
    poll8(hbuf, ev, 0, af);
    poll8(hbuf, ev, 8, af + 8);

    // r-GEMM FIRST (critical path: rh must ship ASAP)
    f32x4 racc = f32x4{0.f,0.f,0.f,0.f};
    #pragma unroll
    for (int kk = 0; kk < 16; ++kk) {
      const int wof = (kk * 64 + kseg * 16) ^ ((fl & 7) << 4);
      bf16x8 b1 = *(const bf16x8*)((const char*)lW + 16384 + fl * 1024 + wof);
      racc = __builtin_amdgcn_mfma_f32_16x16x32_bf16(af[kk], b1, racc, 0, 0, 0);
    }
    float r4[4];
    #pragma unroll
    for (int i = 0; i < 4; ++i) r4[i] = sigmoidf_(racc[i] + urv[i]);
    publish4(rhbuf, ev, r4[0] * hown[0], r4[1] * hown[1],
                        r4[2] * hown[2], r4[3] * hown[3]);

    // z-GEMM overlaps rh propagation to LLC
    f32x4 zacc = f32x4{0.f,0.f,0.f,0.f};
    #pragma unroll
    for (int kk = 0; kk < 16; ++kk) {
      const int wof = (kk * 64 + kseg * 16) ^ ((fl & 7) << 4);
      bf16x8 b0 = *(const bf16x8*)((const char*)lW + fl * 1024 + wof);
      zacc = __builtin_amdgcn_mfma_f32_16x16x32_bf16(af[kk], b0, zacc, 0, 0, 0);
    }
    float z4[4];
    #pragma unroll
    for (int i = 0; i < 4; ++i) z4[i] = sigmoidf_(zacc[i] + uzv[i]);

    // ---- phase 2: gather rh(t), candidate state
    poll8(rhbuf, ev, 0, af);
    poll8(rhbuf, ev, 8, af + 8);

    f32x4 hacc = f32x4{0.f,0.f,0.f,0.f};
    #pragma unroll
    for (int kk = 0; kk < 16; ++kk) {
      const int wof = (kk * 64 + kseg * 16) ^ ((fl & 7) << 4);
      bf16x8 b2 = *(const bf16x8*)((const char*)lW + 32768 + fl * 1024 + wof);
      hacc = __builtin_amdgcn_mfma_f32_16x16x32_bf16(af[kk], b2, hacc, 0, 0, 0);
    }

    float hn[4];
    #pragma unroll
    for (int i = 0; i < 4; ++i) {
      const float nb = tanhf_(hacc[i] + uhv[i]);
      hn[i] = (1.f - z4[i]) * hown[i] + z4[i] * nb;
      hown[i] = hn[i];
    }
    publish4(hbuf, ev + 1u, hn[0], hn[1], hn[2], hn[3]);

    // ---- off-critical-path: output stores + next-step u prefetch
    if (t + 1 < 512) {
      const size_t ub = ((size_t)(t + 1) * 512 + col) * 64 + row0;
      s16x4 az = *(const s16x4*)(ubz + ub);
      s16x4 ar = *(const s16x4*)(ubr + ub);
      s16x4 ah = *(const s16x4*)(ubh + ub);
      #pragma unroll
      for (int i = 0; i < 4; ++i) {
        uzv[i] = h2f((unsigned short)az[i]);
        urv[i] = h2f((unsigned short)ar[i]);
        uhv[i] = h2f((unsigned short)ah[i]);
      }
    }
    {
      const size_t tb = (size_t)t * 64 * 512;
      #pragma unroll
      for (int i = 0; i < 4; ++i) {
        const size_t o = tb + (size_t)(row0 + i) * 512 + col;
        const float v = hn[i];
        out[o] = v;
        out[16777216 + o] = v;
      }
    }
  }
}

extern "C" void kernel_launch(void* const* d_in, const int* in_sizes, int n_in,
                              void* d_out, int out_size, void* d_ws, size_t ws_size,
                              hipStream_t stream) {
  (void)in_sizes; (void)n_in; (void)out_size; (void)ws_size;
  const float* x   = (const float*)d_in[0];
  const float* h0  = (const float*)d_in[1];
  const float* Wz  = (const float*)d_in[2];
  const float* Wzb = (const float*)d_in[3];
  const float* Uz  = (const float*)d_in[4];
  const float* Wr  = (const float*)d_in[6];
  const float* Wrb = (const float*)d_in[7];
  const float* Ur  = (const float*)d_in[8];
  const float* Wh  = (const float*)d_in[10];
  const float* Whb = (const float*)d_in[11];
  const float* Uh  = (const float*)d_in[12];
  const float* gam = (const float*)d_in[14];
  const float* bet = (const float*)d_in[15];
  float* out = (float*)d_out;

  char* ws = (char*)d_ws;
  // layout: [0,128K) hbuf tagged u64[64][256] | [128K,256K) rhbuf |
  //         [256K) ub_z, ub_r, ub_h (fp16 BN-ed + bias, [t][col][b], 32MB ea)
  // No init needed: 0xAA poison (re-applied before every replay) never
  // matches tags 1..513.
  unsigned long long* hbuf  = (unsigned long long*)(ws);
  unsigned long long* rhbuf = (unsigned long long*)(ws + 131072);
  unsigned short*     uzb   = (unsigned short*)(ws + 262144);
  unsigned short*     urb   = (unsigned short*)(ws + 262144 + 33554432);
  unsigned short*     uhb   = (unsigned short*)(ws + 262144 + 2ll * 33554432);

  dim3 gp(512, 8, 3);
  proj_gemm<<<gp, 256, 0, stream>>>(x, Uz, Ur, Uh, Wzb, Wrb, Whb,
                                    gam, bet, uzb, urb, uhb);
  gru_scan<<<dim3(NWG), 256, 0, stream>>>(h0, Wz, Wr, Wh, uzb, urb, uhb,
                                          hbuf, rhbuf, out);
}

// Round 8
// 8970.367 us; speedup vs baseline: 1.1169x; 1.1169x over previous
//
#include <hip/hip_runtime.h>
#include <hip/hip_bf16.h>

// ---------------------------------------------------------------------------
// GRU with per-timestep BatchNorm on the input projections.
//   T=512, B=64, I=H=512.
// Round 7 -> 8: tagged-payload polling regressed 2x because each retry
// re-swept ALL 32 words (16KB/wave/iter, vmcnt(0) each time) -> coherent-path
// congestion doubled FETCH_SIZE and inflated the LLC RT itself. Fix: keep the
// exact r7 protocol (u64 {epoch|2xbf16} self-validating words, no flags, no
// fences, no __syncthreads in the loop) but make the poll STRAGGLER-ONLY:
// initial sweep -> per-lane 32-bit invalid mask -> retry reloads only invalid
// slots (exec-masked), rechecks only those. Valid words stay in registers
// (tags cannot exceed ev during our poll, by the same induction as r5).
// ---------------------------------------------------------------------------

using bf16x8 = __attribute__((ext_vector_type(8))) short;
using f32x4  = __attribute__((ext_vector_type(4))) float;
using fvec4  = __attribute__((ext_vector_type(4))) float;
using s16x4  = __attribute__((ext_vector_type(4))) short;

#define NWG 32

static __device__ __forceinline__ unsigned short f2bf(float f) {
  union { float ff; unsigned int i; } v; v.ff = f;
  unsigned int x = v.i;
  x += 0x7fffu + ((x >> 16) & 1u);   // RNE
  return (unsigned short)(x >> 16);
}
static __device__ __forceinline__ float h2f(unsigned short u) {
  union { unsigned short s; _Float16 h; } v; v.s = u; return (float)v.h;
}
static __device__ __forceinline__ unsigned short f2h(float f) {
  union { unsigned short s; _Float16 h; } v; v.h = (_Float16)f; return v.s;
}
static __device__ __forceinline__ float sigmoidf_(float x) {
  return 1.0f / (1.0f + __expf(-x));
}
static __device__ __forceinline__ float tanhf_(float x) {
  return 2.0f / (1.0f + __expf(-2.0f * x)) - 1.0f;
}

// ---------------- phase 1: ub_m = BN(x @ U_m^T) + W_m_b  (fp16 out) --------
// 64x64 tile = one timestep x batch(64) x 64 cols. BK=64, 4 waves,
// mfma_f32_16x16x32_bf16. BN stats from fp32 accs: shfl over kseg (16 rows)
// then LDS over the 4 waves (64 rows). Output layout [t][col][batch].
__global__ __launch_bounds__(256) void proj_gemm(
    const float* __restrict__ x,
    const float* __restrict__ Uz, const float* __restrict__ Ur,
    const float* __restrict__ Uh,
    const float* __restrict__ Wzb, const float* __restrict__ Wrb,
    const float* __restrict__ Whb,
    const float* __restrict__ gamma, const float* __restrict__ beta,
    unsigned short* __restrict__ ubz, unsigned short* __restrict__ ubr,
    unsigned short* __restrict__ ubh)
{
  const int mt = blockIdx.x, nt = blockIdx.y, mat = blockIdx.z;
  const float* U  = (mat == 0) ? Uz  : (mat == 1 ? Ur  : Uh);
  const float* Wb = (mat == 0) ? Wzb : (mat == 1 ? Wrb : Whb);
  unsigned short* uo = (mat == 0) ? ubz : (mat == 1 ? ubr : ubh);

  __shared__ short lA[4096];   // [64][64] bf16, 128B rows, XOR-swizzled
  __shared__ short lB[4096];

  const int tid = threadIdx.x;
  const int wave = tid >> 6, lane = tid & 63;
  const int fl = lane & 15, kseg = lane >> 4;

  f32x4 acc[4];
  #pragma unroll
  for (int n = 0; n < 4; ++n) acc[n] = f32x4{0.f, 0.f, 0.f, 0.f};

  const float* xb = x + (size_t)mt * 64 * 512;
  const float* Ub = U + (size_t)nt * 64 * 512;

  for (int kt = 0; kt < 8; ++kt) {
    __syncthreads();
    #pragma unroll
    for (int c = 0; c < 2; ++c) {
      const int chunk = tid + 256 * c;       // 0..511
      const int row = chunk >> 3, kc = chunk & 7;
      const int lb = row * 128 + ((kc * 16) ^ ((row & 7) << 4));
      {
        const float* g = xb + (size_t)row * 512 + kt * 64 + kc * 8;
        fvec4 a0 = *(const fvec4*)g, a1 = *(const fvec4*)(g + 4);
        bf16x8 p;
        p[0] = (short)f2bf(a0[0]); p[1] = (short)f2bf(a0[1]);
        p[2] = (short)f2bf(a0[2]); p[3] = (short)f2bf(a0[3]);
        p[4] = (short)f2bf(a1[0]); p[5] = (short)f2bf(a1[1]);
        p[6] = (short)f2bf(a1[2]); p[7] = (short)f2bf(a1[3]);
        *(bf16x8*)((char*)lA + lb) = p;
      }
      {
        const float* g = Ub + (size_t)row * 512 + kt * 64 + kc * 8;
        fvec4 a0 = *(const fvec4*)g, a1 = *(const fvec4*)(g + 4);
        bf16x8 p;
        p[0] = (short)f2bf(a0[0]); p[1] = (short)f2bf(a0[1]);
        p[2] = (short)f2bf(a0[2]); p[3] = (short)f2bf(a0[3]);
        p[4] = (short)f2bf(a1[0]); p[5] = (short)f2bf(a1[1]);
        p[6] = (short)f2bf(a1[2]); p[7] = (short)f2bf(a1[3]);
        *(bf16x8*)((char*)lB + lb) = p;
      }
    }
    __syncthreads();
    #pragma unroll
    for (int kk = 0; kk < 2; ++kk) {
      const int ar = wave * 16 + fl;
      bf16x8 af = *(const bf16x8*)((char*)lA + ar * 128 +
                    ((kk * 64 + kseg * 16) ^ ((ar & 7) << 4)));
      #pragma unroll
      for (int n = 0; n < 4; ++n) {
        const int br = n * 16 + fl;
        bf16x8 bfr = *(const bf16x8*)((char*)lB + br * 128 +
                      ((kk * 64 + kseg * 16) ^ ((br & 7) << 4)));
        acc[n] = __builtin_amdgcn_mfma_f32_16x16x32_bf16(af, bfr, acc[n], 0, 0, 0);
      }
    }
  }

  // ---- BN epilogue: exact batch stats (all 64 rows), from fp32 accs ----
  float sn[4], qn[4];
  #pragma unroll
  for (int n = 0; n < 4; ++n) {
    sn[n] = acc[n][0] + acc[n][1] + acc[n][2] + acc[n][3];
    qn[n] = acc[n][0]*acc[n][0] + acc[n][1]*acc[n][1]
          + acc[n][2]*acc[n][2] + acc[n][3]*acc[n][3];
    sn[n] += __shfl_xor(sn[n], 16); qn[n] += __shfl_xor(qn[n], 16);
    sn[n] += __shfl_xor(sn[n], 32); qn[n] += __shfl_xor(qn[n], 32);
  }
  __syncthreads();                       // all MFMA LDS reads done; reuse lA/lB
  float* sArr = (float*)lA;              // [wave*64 + n*16 + fl]
  float* qArr = (float*)lB;
  if (kseg == 0) {
    #pragma unroll
    for (int n = 0; n < 4; ++n) {
      sArr[wave * 64 + n * 16 + fl] = sn[n];
      qArr[wave * 64 + n * 16 + fl] = qn[n];
    }
  }
  __syncthreads();

  const int c0 = nt * 64;
  const int b0 = wave * 16 + kseg * 4;     // batch base for this thread
  #pragma unroll
  for (int n = 0; n < 4; ++n) {
    const int idx = n * 16 + fl;
    const float s = sArr[idx] + sArr[64+idx] + sArr[128+idx] + sArr[192+idx];
    const float q = qArr[idx] + qArr[64+idx] + qArr[128+idx] + qArr[192+idx];
    const float mu = s * 0.015625f;
    const float rs = rsqrtf(q * 0.015625f - mu * mu + 1e-5f);
    const int col = c0 + idx;
    const float gb  = gamma[col] * rs;
    const float ofs = beta[col] + Wb[col] - gb * mu;   // fold W bias here
    s16x4 pk;
    #pragma unroll
    for (int i = 0; i < 4; ++i)
      pk[i] = (short)f2h(gb * acc[n][i] + ofs);
    // transposed layout: [t][col][batch]
    *(s16x4*)(uo + ((size_t)mt * 512 + col) * 64 + b0) = pk;
  }
}

// ---------------- phase 2: persistent GRU scan (tagged-word exchange) ------
__global__ __launch_bounds__(256) void gru_scan(
    const float* __restrict__ h0,
    const float* __restrict__ Wz, const float* __restrict__ Wr,
    const float* __restrict__ Wh,
    const unsigned short* __restrict__ ubz, const unsigned short* __restrict__ ubr,
    const unsigned short* __restrict__ ubh,
    unsigned long long* __restrict__ hbuf,   // u64[64][256]: {epoch|2xbf16}
    unsigned long long* __restrict__ rhbuf,  // same
    float* __restrict__ out)
{
  const int wg = blockIdx.x;           // owns cols [wg*16, wg*16+16)
  const int tid = threadIdx.x;
  const int wave = tid >> 6, lane = tid & 63;
  const int fl = lane & 15, kseg = lane >> 4;
  const int col = wg * 16 + fl;        // this lane's output column
  const int row0 = wave * 16 + kseg * 4;   // first of 4 C-rows (batch)
  const int hrow = wave * 16 + fl;         // A-frag row (batch)

  // W slices, bf16, [mat][16 rows][512 k], 1KB rows, XOR-swizzled
  __shared__ short lW[24576];

  for (int c = tid; c < 3072; c += 256) {        // 8-elem chunks
    const int m = c >> 10, rem = c & 1023;
    const int r = rem >> 6, kc = rem & 63;
    const float* W = (m == 0) ? Wz : (m == 1 ? Wr : Wh);
    const float* g = W + (size_t)(wg * 16 + r) * 512 + kc * 8;
    bf16x8 p;
    #pragma unroll
    for (int j = 0; j < 8; ++j) p[j] = (short)f2bf(g[j]);
    *(bf16x8*)((char*)lW + m * 16384 + r * 1024 + ((kc * 16) ^ ((r & 7) << 4))) = p;
  }
  __syncthreads();     // lW ready (only intra-WG sync in the kernel)

  // publish 4 bf16 values (rows row0..+3, this lane's col) as tagged words.
  // lane pairs pack (even col | odd col<<16); each thread stores 2 words.
  auto publish4 = [&](unsigned long long* buf, unsigned int ev, const float v0,
                      const float v1, const float v2, const float v3) {
    float vv[4] = {v0, v1, v2, v3};
    #pragma unroll
    for (int i = 0; i < 4; ++i) {
      unsigned int mine = f2bf(vv[i]);
      unsigned int other = (unsigned int)__shfl_xor((int)mine, 1);
      unsigned int word = (fl & 1) ? ((mine << 16) | other)
                                   : (mine | (other << 16));
      if ((fl & 1) == (i & 1))
        __hip_atomic_store(&buf[(row0 + i) * 256 + (col >> 1)],
                           ((unsigned long long)ev << 32) | (unsigned long long)word,
                           __ATOMIC_RELAXED, __HIP_MEMORY_SCOPE_AGENT);
    }
  };

  // poll 8 A-fragments until tags match ev. Initial full sweep, then retry
  // ONLY the invalid slots (per-lane 32-bit mask, exec-masked reloads).
  // Valid slots cannot un-validate: tags never exceed ev during this poll
  // (publish gating induction), so validated words are kept in registers.
  auto poll8m = [&](const unsigned long long* buf, unsigned int ev, int kk0,
                    bf16x8* dst) {
    const unsigned long long* base = buf + hrow * 256 + kseg * 4;
    unsigned long long w[32];
    #pragma unroll
    for (int j = 0; j < 8; ++j) {
      #pragma unroll
      for (int q = 0; q < 4; ++q)
        w[j * 4 + q] = __hip_atomic_load(base + (kk0 + j) * 16 + q,
                                         __ATOMIC_RELAXED,
                                         __HIP_MEMORY_SCOPE_AGENT);
    }
    unsigned int inv = 0u;
    #pragma unroll
    for (int s = 0; s < 32; ++s)
      if ((unsigned int)(w[s] >> 32) != ev) inv |= (1u << s);
    while (inv) {
      #pragma unroll
      for (int s = 0; s < 32; ++s)
        if (inv & (1u << s))
          w[s] = __hip_atomic_load(base + (kk0 + (s >> 2)) * 16 + (s & 3),
                                   __ATOMIC_RELAXED, __HIP_MEMORY_SCOPE_AGENT);
      unsigned int ninv = 0u;
      #pragma unroll
      for (int s = 0; s < 32; ++s)
        if ((inv & (1u << s)) && (unsigned int)(w[s] >> 32) != ev)
          ninv |= (1u << s);
      inv = ninv;
    }
    #pragma unroll
    for (int j = 0; j < 8; ++j) {
      union { unsigned int d[4]; bf16x8 f; } u;
      #pragma unroll
      for (int q = 0; q < 4; ++q) u.d[q] = (unsigned int)w[j * 4 + q];
      dst[j] = u.f;
    }
  };

  // own h columns, fp32, never leave registers
  float hown[4];
  #pragma unroll
  for (int i = 0; i < 4; ++i)
    hown[i] = h0[(size_t)(row0 + i) * 512 + col];
  publish4(hbuf, 1u, hown[0], hown[1], hown[2], hown[3]);

  // prefetch BN-ed u for t=0 (biases folded; layout [t][col][batch])
  float uzv[4], urv[4], uhv[4];
  {
    const size_t ub = ((size_t)col) * 64 + row0;
    s16x4 az = *(const s16x4*)(ubz + ub);
    s16x4 ar = *(const s16x4*)(ubr + ub);
    s16x4 ah = *(const s16x4*)(ubh + ub);
    #pragma unroll
    for (int i = 0; i < 4; ++i) {
      uzv[i] = h2f((unsigned short)az[i]);
      urv[i] = h2f((unsigned short)ar[i]);
      uhv[i] = h2f((unsigned short)ah[i]);
    }
  }

  for (int t = 0; t < 512; ++t) {
    const unsigned int ev = (unsigned int)t + 1u;

    // ---- phase 1: gather h(t) fragments (straggler-only tagged poll)
    bf16x8 af[16];
    poll8m(hbuf, ev, 0, af);
    poll8m(hbuf, ev, 8, af + 8);

    // r-GEMM FIRST (critical path: rh must ship ASAP)
    f32x4 racc = f32x4{0.f,0.f,0.f,0.f};
    #pragma unroll
    for (int kk = 0; kk < 16; ++kk) {
      const int wof = (kk * 64 + kseg * 16) ^ ((fl & 7) << 4);
      bf16x8 b1 = *(const bf16x8*)((const char*)lW + 16384 + fl * 1024 + wof);
      racc = __builtin_amdgcn_mfma_f32_16x16x32_bf16(af[kk], b1, racc, 0, 0, 0);
    }
    float r4[4];
    #pragma unroll
    for (int i = 0; i < 4; ++i) r4[i] = sigmoidf_(racc[i] + urv[i]);
    publish4(rhbuf, ev, r4[0] * hown[0], r4[1] * hown[1],
                        r4[2] * hown[2], r4[3] * hown[3]);

    // z-GEMM overlaps rh propagation to LLC
    f32x4 zacc = f32x4{0.f,0.f,0.f,0.f};
    #pragma unroll
    for (int kk = 0; kk < 16; ++kk) {
      const int wof = (kk * 64 + kseg * 16) ^ ((fl & 7) << 4);
      bf16x8 b0 = *(const bf16x8*)((const char*)lW + fl * 1024 + wof);
      zacc = __builtin_amdgcn_mfma_f32_16x16x32_bf16(af[kk], b0, zacc, 0, 0, 0);
    }
    float z4[4];
    #pragma unroll
    for (int i = 0; i < 4; ++i) z4[i] = sigmoidf_(zacc[i] + uzv[i]);

    // ---- phase 2: gather rh(t), candidate state
    poll8m(rhbuf, ev, 0, af);
    poll8m(rhbuf, ev, 8, af + 8);

    f32x4 hacc = f32x4{0.f,0.f,0.f,0.f};
    #pragma unroll
    for (int kk = 0; kk < 16; ++kk) {
      const int wof = (kk * 64 + kseg * 16) ^ ((fl & 7) << 4);
      bf16x8 b2 = *(const bf16x8*)((const char*)lW + 32768 + fl * 1024 + wof);
      hacc = __builtin_amdgcn_mfma_f32_16x16x32_bf16(af[kk], b2, hacc, 0, 0, 0);
    }

    float hn[4];
    #pragma unroll
    for (int i = 0; i < 4; ++i) {
      const float nb = tanhf_(hacc[i] + uhv[i]);
      hn[i] = (1.f - z4[i]) * hown[i] + z4[i] * nb;
      hown[i] = hn[i];
    }
    publish4(hbuf, ev + 1u, hn[0], hn[1], hn[2], hn[3]);

    // ---- off-critical-path: output stores + next-step u prefetch
    if (t + 1 < 512) {
      const size_t ub = ((size_t)(t + 1) * 512 + col) * 64 + row0;
      s16x4 az = *(const s16x4*)(ubz + ub);
      s16x4 ar = *(const s16x4*)(ubr + ub);
      s16x4 ah = *(const s16x4*)(ubh + ub);
      #pragma unroll
      for (int i = 0; i < 4; ++i) {
        uzv[i] = h2f((unsigned short)az[i]);
        urv[i] = h2f((unsigned short)ar[i]);
        uhv[i] = h2f((unsigned short)ah[i]);
      }
    }
    {
      const size_t tb = (size_t)t * 64 * 512;
      #pragma unroll
      for (int i = 0; i < 4; ++i) {
        const size_t o = tb + (size_t)(row0 + i) * 512 + col;
        const float v = hn[i];
        out[o] = v;
        out[16777216 + o] = v;
      }
    }
  }
}

extern "C" void kernel_launch(void* const* d_in, const int* in_sizes, int n_in,
                              void* d_out, int out_size, void* d_ws, size_t ws_size,
                              hipStream_t stream) {
  (void)in_sizes; (void)n_in; (void)out_size; (void)ws_size;
  const float* x   = (const float*)d_in[0];
  const float* h0  = (const float*)d_in[1];
  const float* Wz  = (const float*)d_in[2];
  const float* Wzb = (const float*)d_in[3];
  const float* Uz  = (const float*)d_in[4];
  const float* Wr  = (const float*)d_in[6];
  const float* Wrb = (const float*)d_in[7];
  const float* Ur  = (const float*)d_in[8];
  const float* Wh  = (const float*)d_in[10];
  const float* Whb = (const float*)d_in[11];
  const float* Uh  = (const float*)d_in[12];
  const float* gam = (const float*)d_in[14];
  const float* bet = (const float*)d_in[15];
  float* out = (float*)d_out;

  char* ws = (char*)d_ws;
  // layout: [0,128K) hbuf tagged u64[64][256] | [128K,256K) rhbuf |
  //         [256K) ub_z, ub_r, ub_h (fp16 BN-ed + bias, [t][col][b], 32MB ea)
  // No init needed: 0xAA poison (re-applied before every replay) never
  // matches tags 1..513.
  unsigned long long* hbuf  = (unsigned long long*)(ws);
  unsigned long long* rhbuf = (unsigned long long*)(ws + 131072);
  unsigned short*     uzb   = (unsigned short*)(ws + 262144);
  unsigned short*     urb   = (unsigned short*)(ws + 262144 + 33554432);
  unsigned short*     uhb   = (unsigned short*)(ws + 262144 + 2ll * 33554432);

  dim3 gp(512, 8, 3);
  proj_gemm<<<gp, 256, 0, stream>>>(x, Uz, Ur, Uh, Wzb, Wrb, Whb,
                                    gam, bet, uzb, urb, uhb);
  gru_scan<<<dim3(NWG), 256, 0, stream>>>(h0, Wz, Wr, Wh, uzb, urb, uhb,
                                          hbuf, rhbuf, out);
}